// Round 3
// baseline (649.137 us; speedup 1.0000x reference)
//
#include <hip/hip_runtime.h>
#include <cstddef>
#include <cstdint>

// Problem constants: EMBED=1024, NUM_HEADS=16, GQA=4, KV_HEADS=4,
// HEAD_DIM=64, KV_EMBED=256, EPS=1e-3, B=2, T=1024.
#define TSEQ 1024

typedef __attribute__((ext_vector_type(8))) short short8;   // 8 bf16 = 4 VGPRs
typedef __attribute__((ext_vector_type(4))) float floatx4;  // MFMA acc

// Workspace layout (floats):
//  XQ : 2048 x 1024  (2M)
//  XK : 2048 x 256   (0.5M)
//  XVt: 2 x 256 x 1024 (0.5M)  -- V-projection TRANSPOSED: [b][h*64+c][j]
//  XO : 2048 x 1024  (2M)
//  P  : 32 x 1024x1024 (33.55M) -- probs/phi in DIAGONAL layout (see below)
static constexpr size_t OFF_XQ  = 0;
static constexpr size_t OFF_XK  = (size_t)2 * 1024 * 1024;
static constexpr size_t OFF_XVT = OFF_XK + (size_t)512 * 1024;
static constexpr size_t OFF_XO  = OFF_XVT + (size_t)512 * 1024;
static constexpr size_t OFF_P   = OFF_XO + (size_t)2 * 1024 * 1024;

// DIAGONAL LAYOUT (R7): logical cell (r, c) of each z's 1024x1024 matrix is
// stored at Pw[(r + (c>>4)) & 1023][c]. The monotonic-recurrence wavefront
// (lane t owns cols [16t,16t+16), processes row r = s - t at step s) reads
// and writes ONE contiguous 4KB storage row (s & 1023) per step, in place.
// The mod-1024 wrap is a bijection: blocks overwritten at step m (lanes
// t <= m) are exactly the blocks NOT consumed at step m+1024 (lanes t > m).
// Scores writes C and PV reads A through the same (row + (col>>4)) & 1023
// shift; both keep their original per-instruction coalescing.
//
// R8: R7 measured 730 cy/step vs ~130 cy of true serial chain. Diagnosis:
// per-step global loads (prefetch) interleaved with per-step global stores
// to the SAME may-aliasing buffer force compiler load-after-store ordering
// (~500-600 cy/step). Fix: stage p through LDS in 8-row chunks with
// global_load_lds (double-buffered, one vmcnt drain per chunk); per-step
// global traffic is then STORES ONLY.

// ---------------------------------------------------------------------------
// fp32 -> bf16 hi/lo split (RNE). x ≈ hi + lo with residual ~2^-17 |x|.
// ---------------------------------------------------------------------------
__device__ __forceinline__ void cvt_hi_lo(float x, unsigned short& hi,
                                          unsigned short& lo) {
  unsigned u = __float_as_uint(x);
  unsigned rh = (u + 0x7FFFu + ((u >> 16) & 1u)) & 0xFFFF0000u;
  hi = (unsigned short)(rh >> 16);
  float xl = x - __uint_as_float(rh);
  unsigned ul = __float_as_uint(xl);
  unsigned rl = ul + 0x7FFFu + ((ul >> 16) & 1u);
  lo = (unsigned short)(rl >> 16);
}

// ---------------------------------------------------------------------------
// Unified NT GEMM core, MFMA bf16x3 (R5-proven).
// ADIAG: A row index gets + (k>>4) & 1023 (reads diagonal-layout matrix).
// CDIAG: C row index gets + (col>>4) & 1023 (writes diagonal-layout matrix).
// ---------------------------------------------------------------------------
template <int EPI, int ADIAG, int CDIAG>
__device__ __forceinline__ void mfma_nt_core(
    const float* __restrict__ A, int lda,
    const float* __restrict__ B, int ldb,
    float* __restrict__ C, int ldc, int K,
    const float* __restrict__ bias)
{
  __shared__ __align__(16) unsigned short Ah[64][40];
  __shared__ __align__(16) unsigned short Al[64][40];
  __shared__ __align__(16) unsigned short Bh[64][40];
  __shared__ __align__(16) unsigned short Bl[64][40];

  const int bm = blockIdx.y << 6;
  const int bn = blockIdx.x << 6;
  const int tid  = threadIdx.x;
  const int lane = tid & 63;
  const int wave = tid >> 6;        // 0..3 -> row sub-tile
  const int m16  = lane & 15;
  const int quad = lane >> 4;

  const int srow = tid >> 2;        // staging: row 0..63
  const int skq  = (tid & 3) << 3;  // staging: k offset 0,8,16,24

  floatx4 acc[4];
#pragma unroll
  for (int c = 0; c < 4; ++c) acc[c] = (floatx4){0.f, 0.f, 0.f, 0.f};

  for (int k0 = 0; k0 < K; k0 += 32) {
    {
      const int kq = k0 + skq;
      int arow = bm + srow;
      if (ADIAG) arow = (arow + (kq >> 4)) & 1023;
      const float* ap = A + (size_t)arow * lda + kq;
      const float* bp = B + (size_t)(bn + srow) * ldb + kq;
      float av[8] __attribute__((aligned(16)));
      float bv[8] __attribute__((aligned(16)));
      *(float4*)&av[0] = *(const float4*)(ap);
      *(float4*)&av[4] = *(const float4*)(ap + 4);
      *(float4*)&bv[0] = *(const float4*)(bp);
      *(float4*)&bv[4] = *(const float4*)(bp + 4);
      short8 vah, valo, vbh, vblo;
#pragma unroll
      for (int e = 0; e < 8; ++e) {
        unsigned short h, l;
        cvt_hi_lo(av[e], h, l);
        vah[e] = (short)h; valo[e] = (short)l;
        cvt_hi_lo(bv[e], h, l);
        vbh[e] = (short)h; vblo[e] = (short)l;
      }
      *(short8*)&Ah[srow][skq] = vah;
      *(short8*)&Al[srow][skq] = valo;
      *(short8*)&Bh[srow][skq] = vbh;
      *(short8*)&Bl[srow][skq] = vblo;
    }
    __syncthreads();

    const int arow = (wave << 4) + m16;
    const short8 a_h = *(const short8*)&Ah[arow][quad << 3];
    const short8 a_l = *(const short8*)&Al[arow][quad << 3];
#pragma unroll
    for (int c = 0; c < 4; ++c) {
      const int brow = (c << 4) + m16;
      const short8 b_h = *(const short8*)&Bh[brow][quad << 3];
      const short8 b_l = *(const short8*)&Bl[brow][quad << 3];
      acc[c] = __builtin_amdgcn_mfma_f32_16x16x32_bf16(a_h, b_h, acc[c], 0, 0, 0);
      acc[c] = __builtin_amdgcn_mfma_f32_16x16x32_bf16(a_h, b_l, acc[c], 0, 0, 0);
      acc[c] = __builtin_amdgcn_mfma_f32_16x16x32_bf16(a_l, b_h, acc[c], 0, 0, 0);
    }
    __syncthreads();
  }

#pragma unroll
  for (int c = 0; c < 4; ++c) {
#pragma unroll
    for (int r = 0; r < 4; ++r) {
      const int row = (wave << 4) + (quad << 2) + r;
      const int col = (c << 4) + m16;
      float v = acc[c][r];
      if (EPI == 0) { if (bias) v += bias[bn + col]; }
      if (EPI == 1) { v += bias[bm + row]; }
      if (EPI == 2) {
        v = 1.0f / (1.0f + expf(-v));
        v = fminf(fmaxf(v, 0.001f), 0.999f);
      }
      int crow = bm + row;
      if (CDIAG) crow = (crow + ((bn + col) >> 4)) & 1023;
      C[(size_t)crow * ldc + (bn + col)] = v;
    }
  }
}

__global__ __launch_bounds__(256) void gemm_nt_mfma_k(
    const float* __restrict__ A, int lda, const float* __restrict__ W, int ldw,
    const float* __restrict__ bias, float* __restrict__ C, int ldc, int K)
{
  mfma_nt_core<0, 0, 0>(A, lda, W, ldw, C, ldc, K, bias);
}

__global__ __launch_bounds__(256) void proj_vt_k(
    const float* __restrict__ vw, const float* __restrict__ value,
    const float* __restrict__ vb, float* __restrict__ XVt)
{
  const int b = blockIdx.z;
  mfma_nt_core<1, 0, 0>(vw, 1024, value + ((size_t)b << 20), 1024,
                        XVt + (size_t)b * 256 * 1024, 1024, 1024, vb);
}

// scores: writes P in DIAGONAL layout (CDIAG=1)
__global__ __launch_bounds__(256) void scores_mfma_k(
    const float* __restrict__ XQ, const float* __restrict__ XK,
    float* __restrict__ P)
{
  const int z = blockIdx.z;
  const int b = z >> 4;
  mfma_nt_core<2, 0, 1>(XQ + ((size_t)b << 20) + ((size_t)(z & 15) << 6), 1024,
                        XK + (size_t)b * TSEQ * 256 + ((size_t)(z & 3) << 6), 256,
                        P + ((size_t)z << 20), 1024, 64, nullptr);
}

// pv: reads phi (A matrix) from DIAGONAL layout (ADIAG=1)
__global__ __launch_bounds__(256) void pv_mfma_k(
    const float* __restrict__ P, const float* __restrict__ XVt,
    float* __restrict__ XO)
{
  const int z = blockIdx.z;
  const int b = z >> 4;
  mfma_nt_core<0, 1, 0>(P + ((size_t)z << 20), 1024,
                        XVt + (size_t)b * 256 * 1024 + (size_t)(z & 3) * 64 * 1024, 1024,
                        XO + ((size_t)b << 20) + ((size_t)(z & 15) << 6), 1024,
                        1024, nullptr);
}

// ---------------------------------------------------------------------------
// global -> LDS direct (16B per lane). gp is PER-LANE; lds dest is uniform
// base + lane*16 (hardware rule). Our layout is linear so this matches.
// ---------------------------------------------------------------------------
__device__ __forceinline__ void glds16(const float* gp, float* lp) {
  __builtin_amdgcn_global_load_lds(
      (const __attribute__((address_space(1))) unsigned int*)gp,
      (__attribute__((address_space(3))) unsigned int*)lp,
      16, 0, 0);
}

// ---------------------------------------------------------------------------
// Monotonic recurrence, DIAGONAL-WAVEFRONT systolic, LDS-chunked (R8).
// ONE WAVE per z. Lane t owns cols [16t,16t+16); at step s processes row
// r = s - t via the raw recurrence; only cross-lane traffic is 2
// __shfl_up(.,1)/step. p comes from LDS (global_load_lds in 8-row chunks,
// double buffered); phi goes straight to global (stores never stall).
// One s_waitcnt vmcnt(0) per chunk replaces R7's per-step alias stall.
// Cross-lane = __shfl only (DPP failed 3x on gfx950 -- permanently banned).
// ---------------------------------------------------------------------------
#define CHUNK 8
#define NCHUNK 136   // 136*8 = 1088 steps (last step is all-invalid pad)

__global__ __launch_bounds__(64) void mono_rec_k(float* __restrict__ P)
{
  const int z = blockIdx.x;
  float* __restrict__ Pz = P + ((size_t)z << 20);
  const int t = threadIdx.x;     // lane 0..63
  const int col0 = t << 4;       // first owned column

  __shared__ __align__(16) float Lb[2][CHUNK * 1024];   // 2 x 32 KB

  float b[16];                   // carry: b[c] = phi[r-1,c] * p[r-1,c]
#pragma unroll
  for (int c = 0; c < 16; ++c) b[c] = 0.0f;
  float p15h = 0.0f, phi15h = 0.0f;   // col-15 values held for lane t+1

  // prologue: prefetch chunk 0 (storage rows 0..7) into Lb[0]
#pragma unroll
  for (int j = 0; j < CHUNK; ++j) {
#pragma unroll
    for (int sg = 0; sg < 4; ++sg) {
      glds16(Pz + ((size_t)j << 10) + (sg << 8) + (t << 2),
             &Lb[0][(j << 10) + (sg << 8)]);
    }
  }

  int cur = 0;
  for (int ck = 0; ck < NCHUNK; ++ck) {
    // wait for current chunk's glds (and drain old stores)
    asm volatile("s_waitcnt vmcnt(0)" ::: "memory");
    __builtin_amdgcn_sched_barrier(0);

    // issue prefetch of chunk ck+1 into the other buffer
    if (ck + 1 < NCHUNK) {
      const int s0n = (ck + 1) << 3;
      float* lb = &Lb[cur ^ 1][0];
#pragma unroll
      for (int j = 0; j < CHUNK; ++j) {
        const int row = (s0n + j) & 1023;
#pragma unroll
        for (int sg = 0; sg < 4; ++sg) {
          glds16(Pz + ((size_t)row << 10) + (sg << 8) + (t << 2),
                 lb + (j << 10) + (sg << 8));
        }
      }
    }

    // prime step-0 p block from LDS
    float pc[16];
    {
      const float* lr = &Lb[cur][col0];
#pragma unroll
      for (int q = 0; q < 4; ++q)
        *(float4*)&pc[4 * q] = *(const float4*)(lr + 4 * q);
    }

    const int s0 = ck << 3;
#pragma unroll
    for (int j = 0; j < CHUNK; ++j) {
      const int s = s0 + j;

      float p[16];
#pragma unroll
      for (int c = 0; c < 16; ++c) p[c] = pc[c];

      // prefetch next step's p block from LDS (hides ds latency under chain)
      if (j + 1 < CHUNK) {
        const float* lr = &Lb[cur][((j + 1) << 10) + col0];
#pragma unroll
        for (int q = 0; q < 4; ++q)
          *(float4*)&pc[4 * q] = *(const float4*)(lr + 4 * q);
      }

      // boundary values from lane t-1 (its row-r col 16t-1, made at s-1).
      // Executed unconditionally so source lanes are active in the shuffle.
      const float phiL = __shfl_up(phi15h, 1);
      const float pL   = __shfl_up(p15h, 1);

      const int r = s - t;
      if (r >= 0 && r < 1024) {
        float phi[16];
        if (r == 0) {
          // phi[0] = onehot(col 0)
#pragma unroll
          for (int c = 0; c < 16; ++c) phi[c] = 0.0f;
          if (t == 0) phi[0] = 1.0f;
        } else {
          const float H0 = (t == 0) ? 0.0f : (1.0f - pL);
          float x = fmaf(H0, phiL, b[0]);
          phi[0] = x;
#pragma unroll
          for (int c = 1; c < 16; ++c) {
            x = fmaf(1.0f - p[c - 1], x, b[c]);
            phi[c] = x;
          }
        }
        // next-row carry + neighbor holds
#pragma unroll
        for (int c = 0; c < 16; ++c) b[c] = phi[c] * p[c];
        p15h   = p[15];
        phi15h = phi[15];
        // write phi over p's cells in global (in-place, coalesced).
        // Stores never wait; the only load-after-store point is the
        // once-per-chunk glds batch above.
        float* spr = Pz + ((size_t)(s & 1023) << 10) + col0;
#pragma unroll
        for (int q = 0; q < 4; ++q)
          *(float4*)(spr + 4 * q) = *(float4*)&phi[4 * q];
      }
    }
    cur ^= 1;
  }
}

// ---------------------------------------------------------------------------
extern "C" void kernel_launch(void* const* d_in, const int* in_sizes, int n_in,
                              void* d_out, int out_size, void* d_ws, size_t ws_size,
                              hipStream_t stream)
{
  const float* query = (const float*)d_in[0];
  const float* key   = (const float*)d_in[1];
  const float* value = (const float*)d_in[2];
  const float* ipw   = (const float*)d_in[3];   // (1536,1024)
  const float* ipb   = (const float*)d_in[4];   // (1536,)
  const float* opw   = (const float*)d_in[5];   // (1024,1024)
  const float* opb   = (const float*)d_in[6];   // (1024,)
  float* out = (float*)d_out;
  float* ws  = (float*)d_ws;

  float* XQ  = ws + OFF_XQ;
  float* XK  = ws + OFF_XK;
  float* XVt = ws + OFF_XVT;
  float* XO  = ws + OFF_XO;
  float* P   = ws + OFF_P;

  // in-projections (MFMA bf16x3)
  gemm_nt_mfma_k<<<dim3(16, 32), 256, 0, stream>>>(
      query, 1024, ipw, 1024, ipb, XQ, 1024, 1024);
  gemm_nt_mfma_k<<<dim3(4, 32), 256, 0, stream>>>(
      key, 1024, ipw + (size_t)1024 * 1024, 1024, ipb + 1024, XK, 256, 1024);
  proj_vt_k<<<dim3(16, 4, 2), 256, 0, stream>>>(
      ipw + (size_t)1280 * 1024, value, ipb + 1280, XVt);

  // scores + sigmoid + clip -> P (diagonal layout)
  scores_mfma_k<<<dim3(16, 16, 32), 256, 0, stream>>>(XQ, XK, P);

  // monotonic recurrence in place (diagonal wavefront, LDS-chunked)
  mono_rec_k<<<dim3(32), dim3(64), 0, stream>>>(P);

  // phi @ V -> XO (NT against transposed V; A read through diagonal map)
  pv_mfma_k<<<dim3(1, 16, 32), 256, 0, stream>>>(P, XVt, XO);

  // out-projection
  gemm_nt_mfma_k<<<dim3(16, 32), 256, 0, stream>>>(
      XO, 1024, opw, 1024, opb, out, 1024, 1024);
}